// Round 2
// baseline (564.463 us; speedup 1.0000x reference)
//
#include <hip/hip_runtime.h>

// MultiHashEncoding: 2-level dense grid trilinear interpolation.
// Level 0: emb0 [16,136,241,16], scale (15,135,240)
// Level 1: emb1 [ 9, 69,121,16], scale ( 8, 68,120)
// out[i] = concat(level0(p_i), level1(p_i))  -> [N, 32] f32
//
// NOTE: reference computes corner = floor(coords + OFFSET) with the f32 add
// BEFORE the floor. floor(c + 1.0f) != floor(c) + 1 when c+1.0f rounds up
// across a binade to exactly the next integer — must replicate bit-exactly.

template<int T, int H, int W>
__device__ __forceinline__ void encode_level(float px, float py, float pz,
                                             const float* __restrict__ emb,
                                             float* __restrict__ acc) {
    const float cx = px * (float)(T - 1);
    const float cy = py * (float)(H - 1);
    const float cz = pz * (float)(W - 1);
    // corner candidates: floor(c + offset) with f32 add first (bit-exact ref)
    const float fx[2] = { floorf(cx), floorf(cx + 1.0f) };
    const float fy[2] = { floorf(cy), floorf(cy + 1.0f) };
    const float fz[2] = { floorf(cz), floorf(cz + 1.0f) };
#pragma unroll
    for (int c = 0; c < 8; ++c) {
        // corner = clip(floor(coord + offset), 0, dim-1); weight uses CLIPPED corner
        const float gx = fminf(fmaxf(fx[(c >> 2) & 1], 0.0f), (float)(T - 1));
        const float gy = fminf(fmaxf(fy[(c >> 1) & 1], 0.0f), (float)(H - 1));
        const float gz = fminf(fmaxf(fz[c & 1],        0.0f), (float)(W - 1));
        const float w = (1.0f - fabsf(gx - cx)) *
                        (1.0f - fabsf(gy - cy)) *
                        (1.0f - fabsf(gz - cz));
        const int ix = (int)gx, iy = (int)gy, iz = (int)gz;
        // 16 contiguous f32 per grid cell = one 64B cache line = 4x float4
        const float4* __restrict__ e =
            (const float4*)(emb + ((((size_t)ix * H) + iy) * (size_t)W + iz) * 16);
#pragma unroll
        for (int q = 0; q < 4; ++q) {
            const float4 v = e[q];
            acc[4 * q + 0] = fmaf(w, v.x, acc[4 * q + 0]);
            acc[4 * q + 1] = fmaf(w, v.y, acc[4 * q + 1]);
            acc[4 * q + 2] = fmaf(w, v.z, acc[4 * q + 2]);
            acc[4 * q + 3] = fmaf(w, v.w, acc[4 * q + 3]);
        }
    }
}

__global__ __launch_bounds__(256)
void MultiHashEncoding_79860621902018_kernel(const float* __restrict__ pts,
                                             const float* __restrict__ emb0,
                                             const float* __restrict__ emb1,
                                             float* __restrict__ out, int n) {
    const int i = blockIdx.x * blockDim.x + threadIdx.x;
    if (i >= n) return;
    const size_t base = (size_t)i * 3;
    const float px = pts[base + 0];
    const float py = pts[base + 1];
    const float pz = pts[base + 2];

    float acc[32];
#pragma unroll
    for (int k = 0; k < 32; ++k) acc[k] = 0.0f;

    encode_level<16, 136, 241>(px, py, pz, emb0, acc);
    encode_level<9, 69, 121>(px, py, pz, emb1, acc + 16);

    float4* __restrict__ o = (float4*)(out + (size_t)i * 32);
#pragma unroll
    for (int q = 0; q < 8; ++q) {
        o[q] = make_float4(acc[4 * q + 0], acc[4 * q + 1],
                           acc[4 * q + 2], acc[4 * q + 3]);
    }
}

extern "C" void kernel_launch(void* const* d_in, const int* in_sizes, int n_in,
                              void* d_out, int out_size, void* d_ws, size_t ws_size,
                              hipStream_t stream) {
    const float* pts  = (const float*)d_in[0];
    const float* emb0 = (const float*)d_in[1];
    const float* emb1 = (const float*)d_in[2];
    float* out = (float*)d_out;
    const int n = in_sizes[0] / 3;

    const int block = 256;
    const int grid = (n + block - 1) / block;
    MultiHashEncoding_79860621902018_kernel<<<grid, block, 0, stream>>>(
        pts, emb0, emb1, out, n);
}

// Round 4
// 461.741 us; speedup vs baseline: 1.2225x; 1.2225x over previous
//
#include <hip/hip_runtime.h>

// MultiHashEncoding: 2-level dense grid trilinear interpolation.
// Level 0: emb0 [16,136,241,16], Level 1: emb1 [9,69,121,16]; out [N,32] f32.
//
// Reference semantics (bit-exact): corner = floor(coords + OFFSET) with the
// f32 add BEFORE floor; corner clipped to [0, dim-1]; weight computed from the
// CLIPPED corner.
//
// Perf structure: gather-latency bound (rocprof r2: FETCH 1.8GB, VALUBusy 1.4%,
// VGPR=36 -> ~2 loads in flight/thread). This version pipelines 8 corner
// gathers per q-step with next-q loads issued before current-q FMAs.

typedef float floatx4 __attribute__((ext_vector_type(4)));

template<int T, int H, int W>
__device__ __forceinline__ void encode_level(float px, float py, float pz,
                                             const float* __restrict__ emb,
                                             float* __restrict__ out_half) {
    const float cx = px * (float)(T - 1);
    const float cy = py * (float)(H - 1);
    const float cz = pz * (float)(W - 1);
    const float fx[2] = { floorf(cx), floorf(cx + 1.0f) };
    const float fy[2] = { floorf(cy), floorf(cy + 1.0f) };
    const float fz[2] = { floorf(cz), floorf(cz + 1.0f) };

    float w[8];
    const floatx4* e[8];
#pragma unroll
    for (int c = 0; c < 8; ++c) {
        const float gx = fminf(fmaxf(fx[(c >> 2) & 1], 0.0f), (float)(T - 1));
        const float gy = fminf(fmaxf(fy[(c >> 1) & 1], 0.0f), (float)(H - 1));
        const float gz = fminf(fmaxf(fz[c & 1],        0.0f), (float)(W - 1));
        w[c] = (1.0f - fabsf(gx - cx)) *
               (1.0f - fabsf(gy - cy)) *
               (1.0f - fabsf(gz - cz));
        const int idx = ((int)gx * H + (int)gy) * W + (int)gz;
        e[c] = (const floatx4*)(emb + (size_t)idx * 16);
    }

    float acc[16];
#pragma unroll
    for (int k = 0; k < 16; ++k) acc[k] = 0.0f;

    // Software-pipelined gather: 8 corner loads in flight while previous
    // batch's FMAs retire. All indices compile-time (stays in registers).
    floatx4 v[8];
#pragma unroll
    for (int c = 0; c < 8; ++c) v[c] = e[c][0];

#pragma unroll
    for (int q = 0; q < 4; ++q) {
        floatx4 vn[8];
        if (q < 3) {
#pragma unroll
            for (int c = 0; c < 8; ++c) vn[c] = e[c][q + 1];
        }
#pragma unroll
        for (int c = 0; c < 8; ++c) {
            acc[4 * q + 0] = fmaf(w[c], v[c].x, acc[4 * q + 0]);
            acc[4 * q + 1] = fmaf(w[c], v[c].y, acc[4 * q + 1]);
            acc[4 * q + 2] = fmaf(w[c], v[c].z, acc[4 * q + 2]);
            acc[4 * q + 3] = fmaf(w[c], v[c].w, acc[4 * q + 3]);
        }
        if (q < 3) {
#pragma unroll
            for (int c = 0; c < 8; ++c) v[c] = vn[c];
        }
    }

    // Streaming output: non-temporal, don't pollute L2 (keep it for emb).
    floatx4* o = (floatx4*)out_half;
#pragma unroll
    for (int q = 0; q < 4; ++q) {
        floatx4 r = { acc[4 * q + 0], acc[4 * q + 1],
                      acc[4 * q + 2], acc[4 * q + 3] };
        __builtin_nontemporal_store(r, &o[q]);
    }
}

__global__ __launch_bounds__(256, 4)
void MultiHashEncoding_79860621902018_kernel(const float* __restrict__ pts,
                                             const float* __restrict__ emb0,
                                             const float* __restrict__ emb1,
                                             float* __restrict__ out, int n) {
    const int i = blockIdx.x * blockDim.x + threadIdx.x;
    if (i >= n) return;
    const size_t base = (size_t)i * 3;
    const float px = pts[base + 0];
    const float py = pts[base + 1];
    const float pz = pts[base + 2];

    float* row = out + (size_t)i * 32;
    encode_level<16, 136, 241>(px, py, pz, emb0, row);
    encode_level<9, 69, 121>(px, py, pz, emb1, row + 16);
}

extern "C" void kernel_launch(void* const* d_in, const int* in_sizes, int n_in,
                              void* d_out, int out_size, void* d_ws, size_t ws_size,
                              hipStream_t stream) {
    const float* pts  = (const float*)d_in[0];
    const float* emb0 = (const float*)d_in[1];
    const float* emb1 = (const float*)d_in[2];
    float* out = (float*)d_out;
    const int n = in_sizes[0] / 3;

    const int block = 256;
    const int grid = (n + block - 1) / block;
    MultiHashEncoding_79860621902018_kernel<<<grid, block, 0, stream>>>(
        pts, emb0, emb1, out, n);
}

// Round 5
// 178.353 us; speedup vs baseline: 3.1649x; 2.5889x over previous
//
#include <hip/hip_runtime.h>

// MultiHashEncoding: 2-level dense grid trilinear interpolation.
// Level 0: emb0 [16,136,241,16], Level 1: emb1 [9,69,121,16]; out [N,32] f32.
//
// Reference semantics (bit-exact): corner = floor(coords + OFFSET) with the
// f32 add BEFORE floor; corner clipped to [0, dim-1]; weight computed from the
// CLIPPED corner.
//
// Parallelization: 16 lanes = 1 point; lane d owns embedding dim d. Each
// corner gather is then 16 lanes x 4B contiguous = ONE 64B transaction
// (vs 4 per corner with thread-per-point). Round-4 evidence: VALUBusy 1.7%,
// VGPR=36, FETCH 1.17GB -> transaction-rate bound, so cut transactions 4x
// and let each thread keep 16 scalar loads in flight.

template<int T, int H, int W>
__device__ __forceinline__ void level_addr_w(float px, float py, float pz, int d,
                                             int* __restrict__ off,
                                             float* __restrict__ w) {
    const float cx = px * (float)(T - 1);
    const float cy = py * (float)(H - 1);
    const float cz = pz * (float)(W - 1);
    const float fx[2] = { floorf(cx), floorf(cx + 1.0f) };
    const float fy[2] = { floorf(cy), floorf(cy + 1.0f) };
    const float fz[2] = { floorf(cz), floorf(cz + 1.0f) };
#pragma unroll
    for (int c = 0; c < 8; ++c) {
        const float gx = fminf(fmaxf(fx[(c >> 2) & 1], 0.0f), (float)(T - 1));
        const float gy = fminf(fmaxf(fy[(c >> 1) & 1], 0.0f), (float)(H - 1));
        const float gz = fminf(fmaxf(fz[c & 1],        0.0f), (float)(W - 1));
        w[c] = (1.0f - fabsf(gx - cx)) *
               (1.0f - fabsf(gy - cy)) *
               (1.0f - fabsf(gz - cz));
        off[c] = (((int)gx * H + (int)gy) * W + (int)gz) * 16 + d;
    }
}

__global__ __launch_bounds__(256)
void MultiHashEncoding_79860621902018_kernel(const float* __restrict__ pts,
                                             const float* __restrict__ emb0,
                                             const float* __restrict__ emb1,
                                             float* __restrict__ out, int n) {
    const int g = blockIdx.x * blockDim.x + threadIdx.x;
    const int p = g >> 4;   // point index
    const int d = g & 15;   // embedding dim owned by this lane
    if (p >= n) return;

    const size_t base = (size_t)p * 3;
    const float px = pts[base + 0];
    const float py = pts[base + 1];
    const float pz = pts[base + 2];

    int   o0[8], o1[8];
    float w0[8], w1[8];
    level_addr_w<16, 136, 241>(px, py, pz, d, o0, w0);
    level_addr_w<9, 69, 121>(px, py, pz, d, o1, w1);

    // Issue all 16 independent gathers before any use: 16 loads in flight.
    float v0[8], v1[8];
#pragma unroll
    for (int c = 0; c < 8; ++c) v0[c] = emb0[o0[c]];
#pragma unroll
    for (int c = 0; c < 8; ++c) v1[c] = emb1[o1[c]];

    float a0 = 0.0f, a1 = 0.0f;
#pragma unroll
    for (int c = 0; c < 8; ++c) a0 = fmaf(w0[c], v0[c], a0);
#pragma unroll
    for (int c = 0; c < 8; ++c) a1 = fmaf(w1[c], v1[c], a1);

    // Coalesced streaming writes; keep L2 for the embedding tables.
    __builtin_nontemporal_store(a0, out + (size_t)p * 32 + d);
    __builtin_nontemporal_store(a1, out + (size_t)p * 32 + 16 + d);
}

extern "C" void kernel_launch(void* const* d_in, const int* in_sizes, int n_in,
                              void* d_out, int out_size, void* d_ws, size_t ws_size,
                              hipStream_t stream) {
    const float* pts  = (const float*)d_in[0];
    const float* emb0 = (const float*)d_in[1];
    const float* emb1 = (const float*)d_in[2];
    float* out = (float*)d_out;
    const int n = in_sizes[0] / 3;

    const int block = 256;
    const long long total = (long long)n * 16;
    const int grid = (int)((total + block - 1) / block);
    MultiHashEncoding_79860621902018_kernel<<<grid, block, 0, stream>>>(
        pts, emb0, emb1, out, n);
}